// Round 11
// baseline (237.402 us; speedup 1.0000x reference)
//
#include <hip/hip_runtime.h>

// Problem constants
constexpr int BN   = 8;            // batch
constexpr int CIN  = 16;
constexpr int COUT = 32;
constexpr int S    = 24;           // spatial edge
constexpr int P    = S * S;        // 576 pixels per plane
constexpr int SP   = 26;           // padded edge
constexpr int PPAD = SP * SP;      // 676
constexpr int NPIX = P * P;        // 331776
constexpr float EPS = 1e-5f;

typedef _Float16 h8 __attribute__((ext_vector_type(8)));
typedef _Float16 h4 __attribute__((ext_vector_type(4)));
typedef float    f4 __attribute__((ext_vector_type(4)));

// Workspace float layout:
// [0,64)       : stats (b*4+g)*2 -> {sum, sumsq}
// [576,5696)   : w1h f16: [tap0..9][co][ci]   (10240 f16; tap 9 = zeros)
// [5696,8256)  : w2h f16: [q][co][k=32]       (5120 f16, q = tap-pair, tap9=0)
// [16384,...)  : V f16: [b][haw][pix][ci]     (84,934,656 f16 = 170 MB)

// Prep: zero stats + build both MFMA weight fragment tables.
__global__ void prep_kernel(const float* __restrict__ w1, const float* __restrict__ w2,
                            float* __restrict__ stats, _Float16* __restrict__ w1h,
                            _Float16* __restrict__ w2h) {
    const int t = threadIdx.x + blockIdx.x * 256;
    if (t < 64) stats[t] = 0.f;
    if (t < COUT * COUT * 9) {   // w1: [co][ci=32][3][3] -> [tap][co][ci]
        const int co = t / 288, rem = t % 288, ci = rem / 9, tap = rem % 9;
        w1h[(tap * 32 + co) * 32 + ci] = (_Float16)w1[t];
    } else if (t < 10 * 32 * 32) {
        w1h[t] = (_Float16)0.f;  // zero tap 9 (selected by border-invalid taps)
    }
    if (t < 5 * 32 * 32) {       // w2: [co][ci=16][3][3] -> [q][co][k]
        const int q = t / 1024, rem = t % 1024, co = rem / 32, k = rem % 32;
        const int tap = 2 * q + k / 16, ci = k % 16;
        w2h[t] = (tap < 9) ? (_Float16)w2[(co * 16 + ci) * 9 + tap] : (_Float16)0.f;
    }
}

// Kernel A: conv over (hb,wb) as implicit GEMM on MFMA.
// One block per (b, ha, wa). x loads are nontemporal (read-once: keep LLC
// for V). V stores stay cached (LLC-resident for conv1).
__global__ __launch_bounds__(256)
void conv2_mfma(const float* __restrict__ x, const _Float16* __restrict__ w2h,
                const float* __restrict__ b2, _Float16* __restrict__ V,
                float* __restrict__ stats)
{
    __shared__ __align__(16) _Float16 tile[PPAD * 16];  // 21632 B
    __shared__ float bs[4][4], bq[4][4];                // [wave][group] partials

    const int tid = threadIdx.x;
    int bid = blockIdx.x;
    bid = (bid & 7) * 576 + (bid >> 3);      // XCD swizzle (4608 = 8*576)
    const int b   = bid / P;
    const int haw = bid - b * P;

    // zero tile (halo stays zero)
    {
        const f4 z = {0.f, 0.f, 0.f, 0.f};
        for (int i = tid; i < PPAD * 16 * 2 / 16; i += 256)
            ((f4*)tile)[i] = z;
    }
    __syncthreads();

    // stage interior: lane-per-pixel, per-ci coalesced nontemporal reads,
    // two swizzled 16B LDS writes per pixel
    for (int p = tid; p < P; p += 256) {
        const int hb = p / 24, wb = p - hb * 24;
        const int pp = (hb + 1) * SP + (wb + 1);
        const float* xp = x + (size_t)(b * CIN) * NPIX + (size_t)haw * P + p;
        h8 lo, hi;
#pragma unroll
        for (int ci = 0; ci < 8; ++ci) {
            lo[ci] = (_Float16)__builtin_nontemporal_load(xp + (size_t)ci * NPIX);
            hi[ci] = (_Float16)__builtin_nontemporal_load(xp + (size_t)(8 + ci) * NPIX);
        }
        const int sw = (pp >> 2) & 1;
        *(h8*)((char*)tile + pp * 32 + ((0 ^ sw) << 4)) = lo;
        *(h8*)((char*)tile + pp * 32 + ((1 ^ sw) << 4)) = hi;
    }
    __syncthreads();

    const int wave = tid >> 6, lane = tid & 63;
    const int lp = lane & 15, lg = lane >> 4;
    const int half = lg & 1;

    // A fragments (weights) : 5 chunks x 2 co-halves
    h8 A[5][2];
#pragma unroll
    for (int q = 0; q < 5; ++q)
#pragma unroll
        for (int h = 0; h < 2; ++h)
            A[q][h] = *(const h8*)(w2h + ((q * 32 + h * 16 + lp) * 32 + lg * 8));

    // per-lane tap offset per chunk (clamped zero-tap for q=4, lg>=2)
    int poff[5];
#pragma unroll
    for (int q = 0; q < 5; ++q) {
        int t = 2 * q + (lg >> 1);
        if (t > 8) t = 8;                     // A half is zero there
        poff[q] = (t / 3 - 1) * SP + (t % 3 - 1);
    }
    // per-chunk padded-pixel base for this lane
    int pbase[9];
#pragma unroll
    for (int c = 0; c < 9; ++c) {
        const int pixel = (wave * 9 + c) * 16 + lp;
        const int hb = pixel / 24, wb = pixel - hb * 24;
        pbase[c] = (hb + 1) * SP + (wb + 1);
    }

    f4 acc[9][2];
    const f4 z = {0.f, 0.f, 0.f, 0.f};
#pragma unroll
    for (int c = 0; c < 9; ++c) { acc[c][0] = z; acc[c][1] = z; }

#pragma unroll
    for (int q = 0; q < 5; ++q) {
#pragma unroll
        for (int c = 0; c < 9; ++c) {
            const int lpix = pbase[c] + poff[q];
            const int sw = (lpix >> 2) & 1;
            const h8 bv = *(const h8*)((const char*)tile + lpix * 32 +
                                       ((half ^ sw) << 4));
            acc[c][0] = __builtin_amdgcn_mfma_f32_16x16x32_f16(A[q][0], bv, acc[c][0], 0, 0, 0);
            acc[c][1] = __builtin_amdgcn_mfma_f32_16x16x32_f16(A[q][1], bv, acc[c][1], 0, 0, 0);
        }
    }

    // epilogue: +bias, GN partial stats, f16 store V [pix][co]
    const f4 bia0 = *(const f4*)(b2 + lg * 4);
    const f4 bia1 = *(const f4*)(b2 + 16 + lg * 4);
    float s0 = 0.f, q0 = 0.f, s1 = 0.f, q1 = 0.f;
    _Float16* vb = V + ((size_t)(b * P + haw) * P) * 32;
#pragma unroll
    for (int c = 0; c < 9; ++c) {
        const int pixel = (wave * 9 + c) * 16 + lp;
        h4 hv0, hv1;
#pragma unroll
        for (int r = 0; r < 4; ++r) {
            const float v0 = acc[c][0][r] + bia0[r];
            const float v1 = acc[c][1][r] + bia1[r];
            s0 += v0; q0 += v0 * v0;
            s1 += v1; q1 += v1 * v1;
            hv0[r] = (_Float16)v0; hv1[r] = (_Float16)v1;
        }
        *(h4*)(vb + (size_t)pixel * 32 + lg * 4)      = hv0;
        *(h4*)(vb + (size_t)pixel * 32 + 16 + lg * 4) = hv1;
    }
    // reduce within each 32-lane half (groups: h*2 + (lane>>5))
#pragma unroll
    for (int off = 16; off > 0; off >>= 1) {
        s0 += __shfl_down(s0, off, 32); q0 += __shfl_down(q0, off, 32);
        s1 += __shfl_down(s1, off, 32); q1 += __shfl_down(q1, off, 32);
    }
    if (lane == 0)  { bs[wave][0] = s0; bq[wave][0] = q0;
                      bs[wave][2] = s1; bq[wave][2] = q1; }
    if (lane == 32) { bs[wave][1] = s0; bq[wave][1] = q0;
                      bs[wave][3] = s1; bq[wave][3] = q1; }
    __syncthreads();
    if (tid < 8) {
        const int g = tid & 3, which = tid >> 2;
        float acc4 = 0.f;
#pragma unroll
        for (int w = 0; w < 4; ++w)
            acc4 += which ? bq[w][g] : bs[w][g];
        atomicAdd(&stats[(b * 4 + g) * 2 + which], acc4);
    }
}

// Kernel C: conv over (ha,wa) plane as implicit GEMM on MFMA.
// R9 paired-tile structure (best: 215us). Changes vs R9:
//  (1) REVERSED tile order within each XCD (j' = 287-j): conv1 reads the
//      most-recently-written V tiles first -> LRU hits on the LLC-resident
//      half of V instead of fetching the evicted half from HBM first.
//  (2) GN finalize merged into the prologue: each lane computes scale/shift
//      for its group from raw stats (identical arithmetic to the old
//      gn_finalize kernel -> bit-identical output); one launch removed.
__global__ __launch_bounds__(256, 2)
void conv1_mfma(const _Float16* __restrict__ V, const _Float16* __restrict__ w1h,
                const float* __restrict__ b1, const float* __restrict__ stats,
                const float* __restrict__ gamma, const float* __restrict__ beta,
                float* __restrict__ out)
{
    __shared__ __align__(16) float ob[8 * P];   // 18432 B

    const int tid  = threadIdx.x;
    const int orig = blockIdx.x;              // 2304 = 8 XCD * 288
    const int xcd  = orig & 7;
    const int j    = 287 - (orig >> 3);       // REVERSED within XCD
    const int b    = xcd;                     // batch == XCD (matches conv2)
    const int ha   = j / 12;
    const int wa0  = (j - ha * 12) * 2;       // even column; pair = wa0, wa0+1
    const int haw0 = ha * 24 + wa0;
    const int wave = tid >> 6, lane = tid & 63;
    const int lp = lane & 15, lg = lane >> 4;
    const int chunk0 = wave * 9;

    // GN finalize in-kernel: lane's 8 channels all belong to group lg.
    const float sum = stats[(b * 4 + lg) * 2 + 0];
    const float ssq = stats[(b * 4 + lg) * 2 + 1];
    const float invN = 1.f / (8.f * (float)NPIX);
    const float mean = sum * invN;
    const float var  = ssq * invN - mean * mean;
    const float rstd = rsqrtf(var + EPS);
    const f4 gm0 = *(const f4*)(gamma + lg * 8);
    const f4 gm1 = *(const f4*)(gamma + lg * 8 + 4);
    const f4 bt0 = *(const f4*)(beta + lg * 8);
    const f4 bt1 = *(const f4*)(beta + lg * 8 + 4);
    h8 scv, shv;
#pragma unroll
    for (int j2 = 0; j2 < 4; ++j2) {
        const float sca = gm0[j2] * rstd, scb = gm1[j2] * rstd;
        scv[j2]     = (_Float16)sca;
        scv[4 + j2] = (_Float16)scb;
        shv[j2]     = (_Float16)(bt0[j2] - mean * sca);
        shv[4 + j2] = (_Float16)(bt1[j2] - mean * scb);
    }

    // lane base pointer at plane (ha, wa0)
    const _Float16* vp0 = V +
        ((size_t)(b * P + haw0) * P + chunk0 * 16 + lp) * 32 + lg * 8;

    f4 acc1[9][2], acc2[9][2];
    const f4 z = {0.f, 0.f, 0.f, 0.f};
#pragma unroll
    for (int c = 0; c < 9; ++c) {
        acc1[c][0] = z; acc1[c][1] = z;
        acc2[c][0] = z; acc2[c][1] = z;
    }

    // plane loop: dh in {-1,0,1} x col in {-1,0,1,2}, fully unrolled ->
    // dh/col (and the tap indices) are compile-time constants.
#pragma unroll
    for (int dh = -1; dh <= 1; ++dh) {
#pragma unroll
        for (int col = -1; col <= 2; ++col) {
            const int ha2 = ha + dh, wa2 = wa0 + col;
            const bool pv = ((unsigned)ha2 < 24u) && ((unsigned)wa2 < 24u);
            if (!pv) continue;               // uniform scalar branch
            const _Float16* vp = vp0 + (dh * 24 + col) * (P * 32);
            // A-fragments; taps compile-time: t1 = 3(dh+1)+col+1, t2 = 3(dh+1)+col
            h8 A1_0, A1_1, A2_0, A2_1;
            if (col <= 1) {
                const int tt = (dh + 1) * 3 + (col + 1);
                A1_0 = *(const h8*)(w1h + ((tt * 32 +      lp) * 32 + lg * 8));
                A1_1 = *(const h8*)(w1h + ((tt * 32 + 16 + lp) * 32 + lg * 8));
            }
            if (col >= 0) {
                const int tt = (dh + 1) * 3 + col;
                A2_0 = *(const h8*)(w1h + ((tt * 32 +      lp) * 32 + lg * 8));
                A2_1 = *(const h8*)(w1h + ((tt * 32 + 16 + lp) * 32 + lg * 8));
            }
            // batch-issue the 9 B-loads for this plane
            h8 raw[9];
#pragma unroll
            for (int c = 0; c < 9; ++c)
                raw[c] = *(const h8*)(vp + c * 512);
            // consume: GN affine + ReLU + up to 4 MFMA per chunk
#pragma unroll
            for (int c = 0; c < 9; ++c) {
                h8 bv = raw[c] * scv + shv;
#pragma unroll
                for (int j3 = 0; j3 < 8; ++j3)
                    bv[j3] = bv[j3] > (_Float16)0 ? bv[j3] : (_Float16)0;
                if (col <= 1) {
                    acc1[c][0] = __builtin_amdgcn_mfma_f32_16x16x32_f16(A1_0, bv, acc1[c][0], 0, 0, 0);
                    acc1[c][1] = __builtin_amdgcn_mfma_f32_16x16x32_f16(A1_1, bv, acc1[c][1], 0, 0, 0);
                }
                if (col >= 0) {
                    acc2[c][0] = __builtin_amdgcn_mfma_f32_16x16x32_f16(A2_0, bv, acc2[c][0], 0, 0, 0);
                    acc2[c][1] = __builtin_amdgcn_mfma_f32_16x16x32_f16(A2_1, bv, acc2[c][1], 0, 0, 0);
                }
            }
        }
    }

    // epilogue: per tile, 4 phases of 8 co; LDS transpose + cooperative
    // full-line NT stores (R7-verified).
    const f4 bia0 = *(const f4*)(b1 + lg * 4);
    const f4 bia1 = *(const f4*)(b1 + 16 + lg * 4);
    auto flush = [&](f4 (&acc)[9][2], int haw) {
#pragma unroll
        for (int g = 0; g < 4; ++g) {
            __syncthreads();                 // WAR vs previous phase's reads
            const int h = g >> 1;
            const int lgbase = 2 * (g & 1);
            if (lg == lgbase || lg == lgbase + 1) {
                const int c0 = (lg - lgbase) * 4;    // co_local base: 0 or 4
#pragma unroll
                for (int c = 0; c < 9; ++c) {
                    const int pix = (chunk0 + c) * 16 + lp;
                    const f4 a = acc[c][h];
                    const f4 bb = h ? bia1 : bia0;
#pragma unroll
                    for (int r = 0; r < 4; ++r)
                        ob[(c0 + r) * P + pix] = a[r] + bb[r];
                }
            }
            __syncthreads();
            float* dst = out + ((size_t)(b * 32 + g * 8) * P + haw) * P;
#pragma unroll
            for (int i = 0; i < 4; ++i) {
                const int idx = tid + i * 256;       // 1024 of 1152 blocks
                const int col = idx / 144, blk = idx - col * 144;
                const f4 v = *(const f4*)&ob[col * P + blk * 4];
                __builtin_nontemporal_store(v, (f4*)(dst + (size_t)col * NPIX + blk * 4));
            }
            if (tid < 128) {                         // remaining 128 blocks
                const int idx = tid + 1024;
                const int col = idx / 144, blk = idx - col * 144;
                const f4 v = *(const f4*)&ob[col * P + blk * 4];
                __builtin_nontemporal_store(v, (f4*)(dst + (size_t)col * NPIX + blk * 4));
            }
        }
    };
    flush(acc1, haw0);
    flush(acc2, haw0 + 1);
}

extern "C" void kernel_launch(void* const* d_in, const int* in_sizes, int n_in,
                              void* d_out, int out_size, void* d_ws, size_t ws_size,
                              hipStream_t stream) {
    const float* x       = (const float*)d_in[0];
    const float* conv1_w = (const float*)d_in[1];
    const float* conv1_b = (const float*)d_in[2];
    const float* conv2_w = (const float*)d_in[3];
    const float* conv2_b = (const float*)d_in[4];
    const float* gamma   = (const float*)d_in[5];
    const float* beta    = (const float*)d_in[6];
    float* out = (float*)d_out;

    float* wsf   = (float*)d_ws;
    float* stats = wsf;                       // 64 floats
    _Float16* w1h = (_Float16*)(wsf + 576);   // 10240 f16 (10 taps)
    _Float16* w2h = (_Float16*)(wsf + 5696);  // 5120 f16
    _Float16* V   = (_Float16*)(wsf + 16384); // 84,934,656 f16

    prep_kernel<<<40, 256, 0, stream>>>(conv1_w, conv2_w, stats, w1h, w2h);
    conv2_mfma<<<BN * P, 256, 0, stream>>>(x, w2h, conv2_b, V, stats);
    conv1_mfma<<<BN * 288, 256, 0, stream>>>(V, w1h, conv1_b, stats,
                                             gamma, beta, out);
}

// Round 12
// 214.536 us; speedup vs baseline: 1.1066x; 1.1066x over previous
//
#include <hip/hip_runtime.h>

// Problem constants
constexpr int BN   = 8;            // batch
constexpr int CIN  = 16;
constexpr int COUT = 32;
constexpr int S    = 24;           // spatial edge
constexpr int P    = S * S;        // 576 pixels per plane
constexpr int SP   = 26;           // padded edge
constexpr int PPAD = SP * SP;      // 676
constexpr int NPIX = P * P;        // 331776
constexpr float EPS = 1e-5f;

typedef _Float16 h8 __attribute__((ext_vector_type(8)));
typedef _Float16 h4 __attribute__((ext_vector_type(4)));
typedef float    f4 __attribute__((ext_vector_type(4)));

// Workspace float layout:
// [0,64)       : stats (b*4+g)*2 -> {sum, sumsq}
// [64,320)     : scale[b*32+c]
// [320,576)    : shift[b*32+c]
// [576,5696)   : w1h f16: [tap0..9][co][ci]   (10240 f16; tap 9 = zeros)
// [5696,8256)  : w2h f16: [q][co][k=32]       (5120 f16, q = tap-pair, tap9=0)
// [16384,...)  : V f16: [b][haw][pix][ci]     (84,934,656 f16 = 170 MB)

// Prep: zero stats + build both MFMA weight fragment tables.
__global__ void prep_kernel(const float* __restrict__ w1, const float* __restrict__ w2,
                            float* __restrict__ stats, _Float16* __restrict__ w1h,
                            _Float16* __restrict__ w2h) {
    const int t = threadIdx.x + blockIdx.x * 256;
    if (t < 64) stats[t] = 0.f;
    if (t < COUT * COUT * 9) {   // w1: [co][ci=32][3][3] -> [tap][co][ci]
        const int co = t / 288, rem = t % 288, ci = rem / 9, tap = rem % 9;
        w1h[(tap * 32 + co) * 32 + ci] = (_Float16)w1[t];
    } else if (t < 10 * 32 * 32) {
        w1h[t] = (_Float16)0.f;  // zero tap 9 (unused; kept for safety)
    }
    if (t < 5 * 32 * 32) {       // w2: [co][ci=16][3][3] -> [q][co][k]
        const int q = t / 1024, rem = t % 1024, co = rem / 32, k = rem % 32;
        const int tap = 2 * q + k / 16, ci = k % 16;
        w2h[t] = (tap < 9) ? (_Float16)w2[(co * 16 + ci) * 9 + tap] : (_Float16)0.f;
    }
}

// Kernel A: conv over (hb,wb) as implicit GEMM on MFMA.
// One block per (b, ha, wa). x loads are nontemporal (read-once: keep LLC
// for V). V stores stay cached (LLC-resident for conv1).
__global__ __launch_bounds__(256)
void conv2_mfma(const float* __restrict__ x, const _Float16* __restrict__ w2h,
                const float* __restrict__ b2, _Float16* __restrict__ V,
                float* __restrict__ stats)
{
    __shared__ __align__(16) _Float16 tile[PPAD * 16];  // 21632 B
    __shared__ float bs[4][4], bq[4][4];                // [wave][group] partials

    const int tid = threadIdx.x;
    int bid = blockIdx.x;
    bid = (bid & 7) * 576 + (bid >> 3);      // XCD swizzle (4608 = 8*576)
    const int b   = bid / P;
    const int haw = bid - b * P;

    // zero tile (halo stays zero)
    {
        const f4 z = {0.f, 0.f, 0.f, 0.f};
        for (int i = tid; i < PPAD * 16 * 2 / 16; i += 256)
            ((f4*)tile)[i] = z;
    }
    __syncthreads();

    // stage interior: lane-per-pixel, per-ci coalesced nontemporal reads,
    // two swizzled 16B LDS writes per pixel
    for (int p = tid; p < P; p += 256) {
        const int hb = p / 24, wb = p - hb * 24;
        const int pp = (hb + 1) * SP + (wb + 1);
        const float* xp = x + (size_t)(b * CIN) * NPIX + (size_t)haw * P + p;
        h8 lo, hi;
#pragma unroll
        for (int ci = 0; ci < 8; ++ci) {
            lo[ci] = (_Float16)__builtin_nontemporal_load(xp + (size_t)ci * NPIX);
            hi[ci] = (_Float16)__builtin_nontemporal_load(xp + (size_t)(8 + ci) * NPIX);
        }
        const int sw = (pp >> 2) & 1;
        *(h8*)((char*)tile + pp * 32 + ((0 ^ sw) << 4)) = lo;
        *(h8*)((char*)tile + pp * 32 + ((1 ^ sw) << 4)) = hi;
    }
    __syncthreads();

    const int wave = tid >> 6, lane = tid & 63;
    const int lp = lane & 15, lg = lane >> 4;
    const int half = lg & 1;

    // A fragments (weights) : 5 chunks x 2 co-halves
    h8 A[5][2];
#pragma unroll
    for (int q = 0; q < 5; ++q)
#pragma unroll
        for (int h = 0; h < 2; ++h)
            A[q][h] = *(const h8*)(w2h + ((q * 32 + h * 16 + lp) * 32 + lg * 8));

    // per-lane tap offset per chunk (clamped zero-tap for q=4, lg>=2)
    int poff[5];
#pragma unroll
    for (int q = 0; q < 5; ++q) {
        int t = 2 * q + (lg >> 1);
        if (t > 8) t = 8;                     // A half is zero there
        poff[q] = (t / 3 - 1) * SP + (t % 3 - 1);
    }
    // per-chunk padded-pixel base for this lane
    int pbase[9];
#pragma unroll
    for (int c = 0; c < 9; ++c) {
        const int pixel = (wave * 9 + c) * 16 + lp;
        const int hb = pixel / 24, wb = pixel - hb * 24;
        pbase[c] = (hb + 1) * SP + (wb + 1);
    }

    f4 acc[9][2];
    const f4 z = {0.f, 0.f, 0.f, 0.f};
#pragma unroll
    for (int c = 0; c < 9; ++c) { acc[c][0] = z; acc[c][1] = z; }

#pragma unroll
    for (int q = 0; q < 5; ++q) {
#pragma unroll
        for (int c = 0; c < 9; ++c) {
            const int lpix = pbase[c] + poff[q];
            const int sw = (lpix >> 2) & 1;
            const h8 bv = *(const h8*)((const char*)tile + lpix * 32 +
                                       ((half ^ sw) << 4));
            acc[c][0] = __builtin_amdgcn_mfma_f32_16x16x32_f16(A[q][0], bv, acc[c][0], 0, 0, 0);
            acc[c][1] = __builtin_amdgcn_mfma_f32_16x16x32_f16(A[q][1], bv, acc[c][1], 0, 0, 0);
        }
    }

    // epilogue: +bias, GN partial stats, f16 store V [pix][co]
    const f4 bia0 = *(const f4*)(b2 + lg * 4);
    const f4 bia1 = *(const f4*)(b2 + 16 + lg * 4);
    float s0 = 0.f, q0 = 0.f, s1 = 0.f, q1 = 0.f;
    _Float16* vb = V + ((size_t)(b * P + haw) * P) * 32;
#pragma unroll
    for (int c = 0; c < 9; ++c) {
        const int pixel = (wave * 9 + c) * 16 + lp;
        h4 hv0, hv1;
#pragma unroll
        for (int r = 0; r < 4; ++r) {
            const float v0 = acc[c][0][r] + bia0[r];
            const float v1 = acc[c][1][r] + bia1[r];
            s0 += v0; q0 += v0 * v0;
            s1 += v1; q1 += v1 * v1;
            hv0[r] = (_Float16)v0; hv1[r] = (_Float16)v1;
        }
        *(h4*)(vb + (size_t)pixel * 32 + lg * 4)      = hv0;
        *(h4*)(vb + (size_t)pixel * 32 + 16 + lg * 4) = hv1;
    }
    // reduce within each 32-lane half (groups: h*2 + (lane>>5))
#pragma unroll
    for (int off = 16; off > 0; off >>= 1) {
        s0 += __shfl_down(s0, off, 32); q0 += __shfl_down(q0, off, 32);
        s1 += __shfl_down(s1, off, 32); q1 += __shfl_down(q1, off, 32);
    }
    if (lane == 0)  { bs[wave][0] = s0; bq[wave][0] = q0;
                      bs[wave][2] = s1; bq[wave][2] = q1; }
    if (lane == 32) { bs[wave][1] = s0; bq[wave][1] = q0;
                      bs[wave][3] = s1; bq[wave][3] = q1; }
    __syncthreads();
    if (tid < 8) {
        const int g = tid & 3, which = tid >> 2;
        float acc4 = 0.f;
#pragma unroll
        for (int w = 0; w < 4; ++w)
            acc4 += which ? bq[w][g] : bs[w][g];
        atomicAdd(&stats[(b * 4 + g) * 2 + which], acc4);
    }
}

// Kernel B: finalize GN -> per (b,c) scale/shift
__global__ void gn_finalize_kernel(const float* __restrict__ stats,
                                   const float* __restrict__ gamma,
                                   const float* __restrict__ beta,
                                   float* __restrict__ scale,
                                   float* __restrict__ shift)
{
    const int t = threadIdx.x;           // 256 = 8b * 32c
    const int b = t >> 5, c = t & 31, g = c >> 3;
    const float sum = stats[(b * 4 + g) * 2 + 0];
    const float ssq = stats[(b * 4 + g) * 2 + 1];
    const float invN = 1.f / (8.f * (float)NPIX);
    const float mean = sum * invN;
    const float var  = ssq * invN - mean * mean;
    const float rstd = rsqrtf(var + EPS);
    const float sc   = gamma[c] * rstd;
    scale[t] = sc;
    shift[t] = beta[c] - mean * sc;
}

// Kernel C: conv over (ha,wa) plane as implicit GEMM on MFMA.
// R9 configuration (session best, 215.0 us) restored verbatim.
// PAIRED-TILE register blocking: one block computes output tiles (ha,wa0)
// and (ha,wa0+1). Union of input planes = 3x4 = 12 (vs 2x9): each B-load
// feeds up to 4 MFMAs, loads & GN/ReLU per output drop 0.67x, block setup
// amortized 2x. dh/col compile-time; border planes skipped by a uniform
// scalar branch (removes exact zeros only -> bit-identical output).
// Ledger (why no further scheduling tricks): depth-window (R5), rolling
// refill (R6, R10), pixel-split occupancy (R8), reversed read order (R11)
// all regressed or were neutral; traffic reduction (this structure) and
// full-line NT stores (R7) are the two levers that held.
__global__ __launch_bounds__(256, 2)
void conv1_mfma(const _Float16* __restrict__ V, const _Float16* __restrict__ w1h,
                const float* __restrict__ b1, const float* __restrict__ scale,
                const float* __restrict__ shift, float* __restrict__ out)
{
    __shared__ __align__(16) float ob[8 * P];   // 18432 B

    const int tid  = threadIdx.x;
    const int orig = blockIdx.x;              // 2304 = 8 XCD * 288
    const int xcd  = orig & 7;
    const int j    = orig >> 3;               // 0..287 within XCD
    const int b    = xcd;                     // batch == XCD
    const int ha   = j / 12;
    const int wa0  = (j - ha * 12) * 2;       // even column; pair = wa0, wa0+1
    const int haw0 = ha * 24 + wa0;
    const int wave = tid >> 6, lane = tid & 63;
    const int lp = lane & 15, lg = lane >> 4;
    const int chunk0 = wave * 9;

    // GN affine params for this lane's 8 ci values (f16 packed math)
    const f4 s0 = *(const f4*)(scale + b * 32 + lg * 8);
    const f4 s1 = *(const f4*)(scale + b * 32 + lg * 8 + 4);
    const f4 t0 = *(const f4*)(shift + b * 32 + lg * 8);
    const f4 t1 = *(const f4*)(shift + b * 32 + lg * 8 + 4);
    h8 scv, shv;
#pragma unroll
    for (int j2 = 0; j2 < 4; ++j2) {
        scv[j2] = (_Float16)s0[j2]; scv[4 + j2] = (_Float16)s1[j2];
        shv[j2] = (_Float16)t0[j2]; shv[4 + j2] = (_Float16)t1[j2];
    }

    // lane base pointer at plane (ha, wa0)
    const _Float16* vp0 = V +
        ((size_t)(b * P + haw0) * P + chunk0 * 16 + lp) * 32 + lg * 8;

    f4 acc1[9][2], acc2[9][2];
    const f4 z = {0.f, 0.f, 0.f, 0.f};
#pragma unroll
    for (int c = 0; c < 9; ++c) {
        acc1[c][0] = z; acc1[c][1] = z;
        acc2[c][0] = z; acc2[c][1] = z;
    }

    // plane loop: dh in {-1,0,1} x col in {-1,0,1,2}, fully unrolled ->
    // dh/col (and the tap indices) are compile-time constants.
#pragma unroll
    for (int dh = -1; dh <= 1; ++dh) {
#pragma unroll
        for (int col = -1; col <= 2; ++col) {
            const int ha2 = ha + dh, wa2 = wa0 + col;
            const bool pv = ((unsigned)ha2 < 24u) && ((unsigned)wa2 < 24u);
            if (!pv) continue;               // uniform scalar branch
            const _Float16* vp = vp0 + (dh * 24 + col) * (P * 32);
            // A-fragments; taps are compile-time: t1 = 3(dh+1)+col+1, t2 = 3(dh+1)+col
            h8 A1_0, A1_1, A2_0, A2_1;
            if (col <= 1) {
                const int tt = (dh + 1) * 3 + (col + 1);
                A1_0 = *(const h8*)(w1h + ((tt * 32 +      lp) * 32 + lg * 8));
                A1_1 = *(const h8*)(w1h + ((tt * 32 + 16 + lp) * 32 + lg * 8));
            }
            if (col >= 0) {
                const int tt = (dh + 1) * 3 + col;
                A2_0 = *(const h8*)(w1h + ((tt * 32 +      lp) * 32 + lg * 8));
                A2_1 = *(const h8*)(w1h + ((tt * 32 + 16 + lp) * 32 + lg * 8));
            }
            // batch-issue the 9 B-loads for this plane
            h8 raw[9];
#pragma unroll
            for (int c = 0; c < 9; ++c)
                raw[c] = *(const h8*)(vp + c * 512);
            // consume: GN affine + ReLU + up to 4 MFMA per chunk
#pragma unroll
            for (int c = 0; c < 9; ++c) {
                h8 bv = raw[c] * scv + shv;
#pragma unroll
                for (int j3 = 0; j3 < 8; ++j3)
                    bv[j3] = bv[j3] > (_Float16)0 ? bv[j3] : (_Float16)0;
                if (col <= 1) {
                    acc1[c][0] = __builtin_amdgcn_mfma_f32_16x16x32_f16(A1_0, bv, acc1[c][0], 0, 0, 0);
                    acc1[c][1] = __builtin_amdgcn_mfma_f32_16x16x32_f16(A1_1, bv, acc1[c][1], 0, 0, 0);
                }
                if (col >= 0) {
                    acc2[c][0] = __builtin_amdgcn_mfma_f32_16x16x32_f16(A2_0, bv, acc2[c][0], 0, 0, 0);
                    acc2[c][1] = __builtin_amdgcn_mfma_f32_16x16x32_f16(A2_1, bv, acc2[c][1], 0, 0, 0);
                }
            }
        }
    }

    // epilogue: per tile, 4 phases of 8 co; LDS transpose + cooperative
    // full-line NT stores (R7-verified).
    const f4 bia0 = *(const f4*)(b1 + lg * 4);
    const f4 bia1 = *(const f4*)(b1 + 16 + lg * 4);
    auto flush = [&](f4 (&acc)[9][2], int haw) {
#pragma unroll
        for (int g = 0; g < 4; ++g) {
            __syncthreads();                 // WAR vs previous phase's reads
            const int h = g >> 1;
            const int lgbase = 2 * (g & 1);
            if (lg == lgbase || lg == lgbase + 1) {
                const int c0 = (lg - lgbase) * 4;    // co_local base: 0 or 4
#pragma unroll
                for (int c = 0; c < 9; ++c) {
                    const int pix = (chunk0 + c) * 16 + lp;
                    const f4 a = acc[c][h];
                    const f4 bb = h ? bia1 : bia0;
#pragma unroll
                    for (int r = 0; r < 4; ++r)
                        ob[(c0 + r) * P + pix] = a[r] + bb[r];
                }
            }
            __syncthreads();
            float* dst = out + ((size_t)(b * 32 + g * 8) * P + haw) * P;
#pragma unroll
            for (int i = 0; i < 4; ++i) {
                const int idx = tid + i * 256;       // 1024 of 1152 blocks
                const int col = idx / 144, blk = idx - col * 144;
                const f4 v = *(const f4*)&ob[col * P + blk * 4];
                __builtin_nontemporal_store(v, (f4*)(dst + (size_t)col * NPIX + blk * 4));
            }
            if (tid < 128) {                         // remaining 128 blocks
                const int idx = tid + 1024;
                const int col = idx / 144, blk = idx - col * 144;
                const f4 v = *(const f4*)&ob[col * P + blk * 4];
                __builtin_nontemporal_store(v, (f4*)(dst + (size_t)col * NPIX + blk * 4));
            }
        }
    };
    flush(acc1, haw0);
    flush(acc2, haw0 + 1);
}

extern "C" void kernel_launch(void* const* d_in, const int* in_sizes, int n_in,
                              void* d_out, int out_size, void* d_ws, size_t ws_size,
                              hipStream_t stream) {
    const float* x       = (const float*)d_in[0];
    const float* conv1_w = (const float*)d_in[1];
    const float* conv1_b = (const float*)d_in[2];
    const float* conv2_w = (const float*)d_in[3];
    const float* conv2_b = (const float*)d_in[4];
    const float* gamma   = (const float*)d_in[5];
    const float* beta    = (const float*)d_in[6];
    float* out = (float*)d_out;

    float* wsf   = (float*)d_ws;
    float* stats = wsf;                       // 64 floats
    float* scale = wsf + 64;                  // 256 floats
    float* shift = wsf + 320;                 // 256 floats
    _Float16* w1h = (_Float16*)(wsf + 576);   // 10240 f16 (10 taps)
    _Float16* w2h = (_Float16*)(wsf + 5696);  // 5120 f16
    _Float16* V   = (_Float16*)(wsf + 16384); // 84,934,656 f16

    prep_kernel<<<40, 256, 0, stream>>>(conv1_w, conv2_w, stats, w1h, w2h);
    conv2_mfma<<<BN * P, 256, 0, stream>>>(x, w2h, conv2_b, V, stats);
    gn_finalize_kernel<<<1, 256, 0, stream>>>(stats, gamma, beta, scale, shift);
    conv1_mfma<<<BN * 288, 256, 0, stream>>>(V, w1h, conv1_b, scale, shift, out);
}